// Round 9
// baseline (111.697 us; speedup 1.0000x reference)
//
#include <hip/hip_runtime.h>

// Problem constants (fixed by reference setup_inputs):
#define NB    8
#define NA    3
#define GSZ   128
#define NC    (NA*5)            // 15
#define NPRED (NA*GSZ*GSZ)      // 49152 preds per image
#define NTOT  (NB*NPRED)        // 393216
#define MGT   64                // gt rows
#define NWRD  (NPRED/32)        // 1536 mask words per image
#define NEGV  (-1e9f)
#define EPSV  (1e-16f)
#define NCHD  (NPRED/256)       // 192 decode chunks per image
#define RSEG  96                // reduce segments per image (512 preds each)
#define RBLK  (NB*RSEG)         // 768 reduce blocks (3 waves/SIMD for TLP)
#define RGRP  8                 // 2-level ticket groups (96 arrivals each)

#define LOG2E 1.442695040888963f
#define LN2   0.693147180559945f

// Fast transcendentals on the gfx950 special-function pipe (~1 ulp).
__device__ __forceinline__ float f_rcp(float x)  { return __builtin_amdgcn_rcpf(x); }
__device__ __forceinline__ float f_log(float x)  { return __builtin_amdgcn_logf(x) * LN2; }
__device__ __forceinline__ float f_tanh(float x) {
    float e = __builtin_amdgcn_exp2f(x * (2.0f * LOG2E));
    return 1.0f - 2.0f * f_rcp(e + 1.0f);
}
__device__ __forceinline__ float f_sigmoid(float x) {
    return f_rcp(1.0f + __builtin_amdgcn_exp2f(-x * LOG2E));
}

// GIoU/IoU exactly mirroring the reference arithmetic order (fp32).
__device__ __forceinline__ void gou_iou(const float4 p, const float4 g,
                                        float& iou, float& gou) {
    float px1 = p.x - p.z * 0.5f, px2 = p.x + p.z * 0.5f;
    float py1 = p.y - p.w * 0.5f, py2 = p.y + p.w * 0.5f;
    float gx1 = g.x - g.z * 0.5f, gx2 = g.x + g.z * 0.5f;
    float gy1 = g.y - g.w * 0.5f, gy2 = g.y + g.w * 0.5f;
    float iw = fmaxf(fminf(px2, gx2) - fmaxf(px1, gx1), 0.0f);
    float ih = fmaxf(fminf(py2, gy2) - fmaxf(py1, gy1), 0.0f);
    float inter = iw * ih;
    float ap = (px2 - px1) * (py2 - py1);
    float ag = (gx2 - gx1) * (gy2 - gy1);
    float un = ap + ag - inter;
    iou = inter / (un + EPSV);
    float cw = fmaxf(px2, gx2) - fminf(px1, gx1);
    float ch = fmaxf(py2, gy2) - fminf(py1, gy1);
    float ac = cw * ch;
    gou = iou - (ac - un) / (ac + EPSV);
}

// K1: decode preds -> pd/conf, fused round-1 per-gt argmax chunk partials,
// AND a 1-bit-per-pred ignore-threshold mask: thr = (fallback-argmax IoU
// > 0.5). For non-tp preds the reference loss consumes ONLY this bit
// (everything else is multiplied by tpf=0), so 48 KB of bits replaces the
// 6.3 MB pd re-read + per-pred GIoU re-scan in k_reduce.
__global__ __launch_bounds__(256) void k_decode(const float* __restrict__ out,
                                                const float* __restrict__ gts,
                                                float4* __restrict__ pd,
                                                float* __restrict__ conf,
                                                unsigned long long* __restrict__ thrbits,
                                                float* __restrict__ pval,
                                                int* __restrict__ ppd,
                                                unsigned* __restrict__ done) {
    const int tid = threadIdx.x;
    const int b = blockIdx.x / NCHD;          // image
    const int ch = blockIdx.x % NCHD;         // chunk within image
    __shared__ float4 Pl[256];                // decoded preds of this chunk
    __shared__ float4 gbA[MGT];
    __shared__ int glist[MGT];
    __shared__ int ng_s;

    if (blockIdx.x == 0 && tid < RGRP + 1) done[tid] = 0u;  // 2-level ticket
    if (tid < MGT) {
        gbA[tid] = make_float4(gts[tid * 5 + 1], gts[tid * 5 + 2],
                               gts[tid * 5 + 3], gts[tid * 5 + 4]);
        bool v = (gts[tid * 5] == (float)b);
        unsigned long long m = __ballot(v);
        if (v) glist[(int)__popcll(m & ((1ull << tid) - 1ull))] = tid;  // ascending j
        if (tid == 0) ng_s = (int)__popcll(m);
    }

    // decode
    const int idx = blockIdx.x * 256 + tid;
    const int p_loc = ch * 256 + tid;         // pred index within image
    int a = p_loc / (GSZ * GSZ), r = p_loc % (GSZ * GSZ);
    int y = r / GSZ, x = r % GSZ;
    const float* base = out + ((((size_t)b * NC + a * 5) * GSZ + y) * GSZ + x);
    const int st = GSZ * GSZ;
    float t0 = base[0], t1 = base[st], t2 = base[2 * st], t3 = base[3 * st], t4 = base[4 * st];
    const float inv_gs = 1.0f / (float)GSZ;   // exact (pow2)
    float4 P;
    P.x = (f_tanh(t0) + 0.5f + (float)x) * inv_gs;
    P.y = (f_tanh(t1) + 0.5f + (float)y) * inv_gs;
    P.z = __builtin_amdgcn_exp2f(-(t2 * t2) * LOG2E);
    P.w = __builtin_amdgcn_exp2f(-(t3 * t3) * LOG2E);
    pd[idx] = P;
    conf[idx] = f_sigmoid(t4);
    Pl[tid] = P;
    __syncthreads();

    // per-pred fallback argmax (P in registers, ascending j, strict > =
    // first max) -> thr bit. gou >= -1 >> NEGV so valid gts beat the init.
    const int ng = ng_s;
    {
        float bg = NEGV, bi = 0.0f;
        for (int m = 0; m < ng; m++) {
            float iu, go; gou_iou(P, gbA[glist[m]], iu, go);
            if (go > bg) { bg = go; bi = iu; }
        }
        bool thr = (ng > 0) && (bi > 0.5f);   // ng==0 -> pd_ious=0 -> thr=0
        unsigned long long tm = __ballot(thr);
        if ((tid & 63) == 0) thrbits[idx >> 6] = tm;
    }

    // per-gt argmax over this 256-pred chunk; wave w handles gts w, w+4, ...
    // Lane l owns preds 4l..4l+3 (ascending) -> strict > keeps first max;
    // cross-lane tiebreak idx-asc -> exact first-occurrence semantics.
    const int wave = tid >> 6, lane = tid & 63;
    for (int m = wave; m < ng; m += 4) {
        float4 g = gbA[glist[m]];
        float bv = NEGV; int bp = 0;
        #pragma unroll
        for (int k = 0; k < 4; k++) {
            int p = lane * 4 + k;
            float iu, go; gou_iou(Pl[p], g, iu, go);
            if (go > bv) { bv = go; bp = p; }
        }
        for (int off = 32; off > 0; off >>= 1) {
            float v2 = __shfl_down(bv, off, 64);
            int   p2 = __shfl_down(bp, off, 64);
            if (v2 > bv || (v2 == bv && p2 < bp)) { bv = v2; bp = p2; }
        }
        if (lane == 0) {
            int j = glist[m];
            pval[j * NCHD + ch] = bv;
            ppd[j * NCHD + ch]  = ch * 256 + bp;   // pred index within image
        }
    }
}

// K2: greedy matching, one workgroup per image. Per-gt state in WAVE-0
// REGISTERS (lane j = gt j); rounds are ballot+shuffle (no LDS latency
// chains); block-wide rescans only for stolen cached argmaxes.
// Replicates the reference while_loop exactly (first-occurrence argmax
// ties, winner scatter-max, first-j Amat selection).
#define MTH 1024
__global__ __launch_bounds__(MTH) void k_match(const float* __restrict__ gts,
                                               const float* __restrict__ pval,
                                               const int* __restrict__ ppd,
                                               const float4* __restrict__ pd,
                                               unsigned* __restrict__ tpbits_g,
                                               int* __restrict__ pidx_g) {
    const int b = blockIdx.x;
    const int tid = threadIdx.x;
    __shared__ unsigned mbits[NWRD];            // matched-pred bitmask
    __shared__ float4 gb[MGT];
    __shared__ float sh_v[MGT];
    __shared__ int   sh_p[MGT];
    __shared__ float sh_rv[16];
    __shared__ int   sh_rp[16];
    __shared__ unsigned long long sh_need;
    __shared__ int sh_cont;

    for (int i = tid; i < NWRD; i += MTH) mbits[i] = 0u;
    if (tid < MGT)
        gb[tid] = make_float4(gts[tid * 5 + 1], gts[tid * 5 + 2],
                              gts[tid * 5 + 3], gts[tid * 5 + 4]);

    // parallel merge of decode's 192 chunk partials -> per-gt seed.
    // 16 threads per gt, 12 chunks each (ascending chunk = ascending pred:
    // strict > + idx-asc tiebreak == exact first-occurrence argmax).
    {
        int jt = tid >> 4, sub = tid & 15;
        float mv = NEGV; int mp = 0x7FFFFFFF;
        #pragma unroll
        for (int k = 0; k < NCHD / 16; k++) {
            int ch = sub * (NCHD / 16) + k;
            float v2 = pval[jt * NCHD + ch];
            int   p2 = ppd [jt * NCHD + ch];
            if (v2 > mv || (v2 == mv && p2 < mp)) { mv = v2; mp = p2; }
        }
        for (int off = 1; off < 16; off <<= 1) {          // xor-butterfly in 16-group
            float v2 = __shfl_xor(mv, off, 64);
            int   p2 = __shfl_xor(mp, off, 64);
            if (v2 > mv || (v2 == mv && p2 < mp)) { mv = v2; mp = p2; }
        }
        if (sub == 0) { sh_v[jt] = mv; sh_p[jt] = mp; }
    }
    __syncthreads();

    // wave-0 per-gt register state (invalid gts carry poisoned seeds from
    // unwritten pval/ppd rows -> mask them so no garbage LDS index forms)
    bool r_valid = false, r_sel = false;
    float r_cval = NEGV; int r_cpd = 0;
    if (tid < 64) {
        r_valid = (gts[tid * 5] == (float)b);
        r_cval = r_valid ? sh_v[tid] : NEGV;
        r_cpd  = r_valid ? sh_p[tid] : 0;
    }
    const float4* pdb = pd + (size_t)b * NPRED;

    for (int round = 0; round < MGT + 2; ++round) {
        if (tid < 64) {
            bool active = r_valid && !r_sel;
            unsigned long long am = __ballot(active);
            bool stolen = active && ((mbits[r_cpd >> 5] >> (r_cpd & 31)) & 1u);
            unsigned long long nm = __ballot(stolen);
            if (tid == 0) { sh_cont = (am != 0ull) ? 1 : 0; sh_need = nm; }
        }
        __syncthreads();
        if (!sh_cont) break;
        unsigned long long need = sh_need;

        // rescans: only gts whose cached best pred got stolen (mask only
        // grows, so an un-stolen cached argmax is still exact).
        while (need) {
            int j = __ffsll((long long)need) - 1; need &= need - 1ull;
            float4 g = gb[j];
            float bv = NEGV; int bp = 0x7FFFFFFF;
            for (int p = tid; p < NPRED; p += MTH) {
                if ((mbits[p >> 5] >> (p & 31)) & 1u) continue;
                float iu, go; gou_iou(pdb[p], g, iu, go);
                if (go > bv) { bv = go; bp = p; }        // strict > : first max
            }
            for (int off = 32; off > 0; off >>= 1) {
                float v2 = __shfl_down(bv, off, 64);
                int   p2 = __shfl_down(bp, off, 64);
                if (v2 > bv || (v2 == bv && p2 < bp)) { bv = v2; bp = p2; }
            }
            if ((tid & 63) == 0) { sh_rv[tid >> 6] = bv; sh_rp[tid >> 6] = bp; }
            __syncthreads();
            if (tid < 64) {
                float v = (tid < 16) ? sh_rv[tid] : NEGV;
                int   p = (tid < 16) ? sh_rp[tid] : 0x7FFFFFFF;
                for (int off = 1; off < 16; off <<= 1) {
                    float v2 = __shfl_xor(v, off, 64);
                    int   p2 = __shfl_xor(p, off, 64);
                    if (v2 > v || (v2 == v && p2 < p)) { v = v2; p = p2; }
                }
                v = __shfl(v, 0, 64); p = __shfl(p, 0, 64);
                if (tid == j) { r_cval = v; r_cpd = p; }
            }
            __syncthreads();
        }

        // conflict resolution, all in wave-0 registers + shuffles.
        if (tid < 64) {
            bool active = r_valid && !r_sel;
            float valj = active ? r_cval : NEGV;     // reference: inactive -> NEG
            int   pdj  = active ? r_cpd  : 0;        // reference: argmax of all-NEG = 0
            // winner[p] = scatter-max of valj over gts with pdj==p
            float w = NEGV;
            for (int j2 = 0; j2 < 64; j2++) {
                float v2 = __shfl(valj, j2, 64);
                int   p2 = __shfl(pdj,  j2, 64);
                if (p2 == pdj) w = fmaxf(w, v2);
            }
            // Amat first-j: first j2 with pdj2==p && valj2>=w
            unsigned long long fm = 0ull;
            for (int j2 = 0; j2 < 64; j2++) {
                float v2 = __shfl(valj, j2, 64);
                int   p2 = __shfl(pdj,  j2, 64);
                if (p2 == pdj && v2 >= w) fm |= (1ull << j2);
            }
            bool win = active && (w > NEGV * 0.5f) && fm &&
                       ((__ffsll((long long)fm) - 1) == tid);
            if (win) {
                r_sel = true;
                atomicOr(&mbits[pdj >> 5], 1u << (pdj & 31));
                pidx_g[(size_t)b * NPRED + pdj] = tid;
            }
        }
        __syncthreads();   // mbits visible to all before next round / rescan
    }
    __syncthreads();
    for (int i = tid; i < NWRD; i += MTH) tpbits_g[b * NWRD + i] = mbits[i];
}

// K3: traffic-thin loss accumulation. Non-tp preds (99.9%): conf (4B) +
// wave-uniform thr/tp bit words — nothing else (the reference multiplies
// all other terms by tpf=0). Tp preds (<=64/image) gather pd+pidx and do
// the full math. fp64 partials; 2-level ticket finalize (96+8 arrivals).
__global__ __launch_bounds__(256) void k_reduce(const float* __restrict__ gts,
                                                const float4* __restrict__ pd,
                                                const float* __restrict__ conf,
                                                const unsigned long long* __restrict__ thrbits,
                                                const unsigned* __restrict__ tpbits,
                                                const int* __restrict__ pidx,
                                                double* __restrict__ partial,
                                                unsigned* __restrict__ done,
                                                float* __restrict__ o) {
    __shared__ float4 gb[MGT];
    __shared__ double wsum[4][9];
    __shared__ int isLast;
    const int tid = threadIdx.x;
    const int b = blockIdx.x / RSEG;
    const int seg = blockIdx.x % RSEG;
    if (tid < MGT)
        gb[tid] = make_float4(gts[tid * 5 + 1], gts[tid * 5 + 2],
                              gts[tid * 5 + 3], gts[tid * 5 + 4]);
    __syncthreads();
    // s: 0 cnt, 1 sxy, 2 swh, 3 sgou, 4 siou, 5 icnt, 6 sbce, 7 sinter, 8 sarea
    double s[9] = {0, 0, 0, 0, 0, 0, 0, 0, 0};
    #pragma unroll
    for (int it = 0; it < 2; ++it) {
        int p = seg * 512 + it * 256 + tid;              // pred within image
        int idx = b * NPRED + p;
        int tp = (tpbits[b * NWRD + (p >> 5)] >> (p & 31)) & 1;
        bool thr = (thrbits[idx >> 6] >> (idx & 63)) & 1;  // wave-uniform word
        float c = conf[idx];
        c = fminf(fmaxf(c, 1e-7f), 1.0f - 1e-7f);
        if (tp) {                                        // rare (<=64/image)
            int j = pidx[idx];
            float4 P = pd[idx];
            float pi, pg; gou_iou(P, gb[j], pi, pg);
            s[0] += 1.0;
            float dx = P.x - gb[j].x, dy = P.y - gb[j].y;
            s[1] += (double)(dx * dx) + (double)(dy * dy);
            float lw = f_log(P.z) - f_log(gb[j].z);
            float lh = f_log(P.w) - f_log(gb[j].w);
            s[2] += (double)(lw * lw) + (double)(lh * lh);
            s[3] += (double)pg;
            s[4] += (double)pi;
        }
        bool ig = (!thr) || tp;                          // tp -> always ignored-in
        if (ig) {
            s[5] += 1.0;
            float bce = tp ? -f_log(c) : -f_log(1.0f - c);
            s[6] += (double)bce;
            if (tp) s[7] += (double)c;
            s[8] += (double)c * (double)c;
        }
    }
    for (int k = 0; k < 9; k++) {
        double v = s[k];
        for (int off = 32; off > 0; off >>= 1) v += __shfl_down(v, off, 64);
        s[k] = v;
    }
    if ((tid & 63) == 0)
        for (int k = 0; k < 9; k++) wsum[tid >> 6][k] = s[k];
    __syncthreads();
    if (tid < 9)
        partial[blockIdx.x * 9 + tid] =
            wsum[0][tid] + wsum[1][tid] + wsum[2][tid] + wsum[3][tid];
    __syncthreads();
    if (tid == 0) {
        __threadfence();                                  // release partials
        isLast = 0;
        int g = blockIdx.x / (RBLK / RGRP);
        unsigned o1 = atomicAdd(&done[g], 1u);            // level-1 ticket
        if (o1 == (RBLK / RGRP) - 1) {
            __threadfence();
            unsigned o2 = atomicAdd(&done[RGRP], 1u);     // level-2 ticket
            if (o2 == RGRP - 1) isLast = 1;
        }
    }
    __syncthreads();
    if (!isLast) return;
    __threadfence();                                      // acquire partials

    double t[9] = {0, 0, 0, 0, 0, 0, 0, 0, 0};
    for (int bb = tid; bb < RBLK; bb += 256)
        for (int k = 0; k < 9; k++) t[k] += partial[bb * 9 + k];
    for (int k = 0; k < 9; k++) {
        double v = t[k];
        for (int off = 32; off > 0; off >>= 1) v += __shfl_down(v, off, 64);
        t[k] = v;
    }
    if ((tid & 63) == 0)
        for (int k = 0; k < 9; k++) wsum[tid >> 6][k] = t[k];
    __syncthreads();
    if (tid == 0) {
        double acc[9];
        for (int k = 0; k < 9; k++)
            acc[k] = wsum[0][k] + wsum[1][k] + wsum[2][k] + wsum[3][k];
        double cnt_raw = acc[0];
        double cnt = cnt_raw > 1.0 ? cnt_raw : 1.0;
        double lxy  = acc[1] / cnt;
        double lwh  = acc[2] / cnt;
        double lgou = 1.0 - acc[3] / cnt;
        double liou = 1.0 - acc[4] / cnt;
        double icnt = acc[5] > 1.0 ? acc[5] : 1.0;
        double lbce = acc[6] / icnt;
        // gt_area = (tpf*ig).sum() == raw tp count (ig superset of tp), UNclamped
        double ldice = 1.0 - (2.0 * acc[7] + 1.0) / (acc[8] + cnt_raw + 1.0);
        double lconf = ldice + lbce;
        double tot = lconf + 2.0 * lgou + lwh + lxy;
        o[0] = (float)lxy;
        o[1] = (float)lwh;
        o[2] = (float)lconf;
        o[3] = (float)liou;
        o[4] = (float)lgou;
        o[5] = (float)tot;
    }
}

extern "C" void kernel_launch(void* const* d_in, const int* in_sizes, int n_in,
                              void* d_out, int out_size, void* d_ws, size_t ws_size,
                              hipStream_t stream) {
    const float* out_t = (const float*)d_in[0];  // [8,15,128,128]
    const float* gts   = (const float*)d_in[1];  // [64,5]
    char* ws = (char*)d_ws;
    size_t off = 0;
    unsigned* done    = (unsigned*)(ws + off);  off += 256;
    double*   partial = (double*)(ws + off);    off += (size_t)RBLK * 9 * 8;    // 55296
    float*    pval    = (float*)(ws + off);     off += (size_t)MGT * NCHD * 4;  // 49152
    int*      ppd     = (int*)(ws + off);       off += (size_t)MGT * NCHD * 4;  // 49152
    unsigned* tpbits  = (unsigned*)(ws + off);  off += (size_t)NB * NWRD * 4;   // 49152
    unsigned long long* thrbits = (unsigned long long*)(ws + off);
    off += (size_t)(NTOT / 64) * 8;                                             // 49152
    int*      pidx    = (int*)(ws + off);       off += (size_t)NTOT * 4;        // 1.5 MB
    off = (off + 15) & ~(size_t)15;
    float4*   pd      = (float4*)(ws + off);    off += (size_t)NTOT * 16;       // 6.3 MB
    float*    conf    = (float*)(ws + off);     off += (size_t)NTOT * 4;        // 1.5 MB
    float* o = (float*)d_out;

    k_decode<<<NTOT / 256, 256, 0, stream>>>(out_t, gts, pd, conf, thrbits, pval, ppd, done);
    k_match <<<NB, MTH, 0, stream>>>(gts, pval, ppd, pd, tpbits, pidx);
    k_reduce<<<RBLK, 256, 0, stream>>>(gts, pd, conf, thrbits, tpbits, pidx, partial, done, o);
}

// Round 10
// 91.913 us; speedup vs baseline: 1.2152x; 1.2152x over previous
//
#include <hip/hip_runtime.h>

// Problem constants (fixed by reference setup_inputs):
#define NB    8
#define NA    3
#define GSZ   128
#define NC    (NA*5)            // 15
#define NPRED (NA*GSZ*GSZ)      // 49152 preds per image
#define NTOT  (NB*NPRED)        // 393216
#define MGT   64                // gt rows
#define NWRD  (NPRED/32)        // 1536 mask words per image
#define NEGV  (-1e9f)
#define EPSV  (1e-16f)
#define NCHD  (NPRED/256)       // 192 decode chunks per image
#define DBLK  (NB*NCHD)         // 1536 decode blocks

#define LOG2E 1.442695040888963f
#define LN2   0.693147180559945f

// Fast transcendentals on the gfx950 special-function pipe (~1 ulp).
__device__ __forceinline__ float f_rcp(float x)  { return __builtin_amdgcn_rcpf(x); }
__device__ __forceinline__ float f_log(float x)  { return __builtin_amdgcn_logf(x) * LN2; }
__device__ __forceinline__ float f_tanh(float x) {
    float e = __builtin_amdgcn_exp2f(x * (2.0f * LOG2E));
    return 1.0f - 2.0f * f_rcp(e + 1.0f);
}
__device__ __forceinline__ float f_sigmoid(float x) {
    return f_rcp(1.0f + __builtin_amdgcn_exp2f(-x * LOG2E));
}

// GIoU/IoU exactly mirroring the reference arithmetic order (fp32).
__device__ __forceinline__ void gou_iou(const float4 p, const float4 g,
                                        float& iou, float& gou) {
    float px1 = p.x - p.z * 0.5f, px2 = p.x + p.z * 0.5f;
    float py1 = p.y - p.w * 0.5f, py2 = p.y + p.w * 0.5f;
    float gx1 = g.x - g.z * 0.5f, gx2 = g.x + g.z * 0.5f;
    float gy1 = g.y - g.w * 0.5f, gy2 = g.y + g.w * 0.5f;
    float iw = fmaxf(fminf(px2, gx2) - fmaxf(px1, gx1), 0.0f);
    float ih = fmaxf(fminf(py2, gy2) - fmaxf(py1, gy1), 0.0f);
    float inter = iw * ih;
    float ap = (px2 - px1) * (py2 - py1);
    float ag = (gx2 - gx1) * (gy2 - gy1);
    float un = ap + ag - inter;
    iou = inter / (un + EPSV);
    float cw = fmaxf(px2, gx2) - fminf(px1, gx1);
    float ch = fmaxf(py2, gy2) - fminf(py1, gy1);
    float ac = cw * ch;
    gou = iou - (ac - un) / (ac + EPSV);
}

// Decode pred p of image b straight from the raw tensor. Used identically in
// all kernels -> bit-identical P everywhere (no materialized pd array).
__device__ __forceinline__ float4 decode_P(const float* __restrict__ out,
                                           int b, int p) {
    int a = p / (GSZ * GSZ), r = p % (GSZ * GSZ);
    int y = r / GSZ, x = r % GSZ;
    const float* base = out + ((((size_t)b * NC + a * 5) * GSZ + y) * GSZ + x);
    const int st = GSZ * GSZ;
    float t0 = base[0], t1 = base[st], t2 = base[2 * st], t3 = base[3 * st];
    const float inv_gs = 1.0f / (float)GSZ;   // exact (pow2)
    float4 P;
    P.x = (f_tanh(t0) + 0.5f + (float)x) * inv_gs;
    P.y = (f_tanh(t1) + 0.5f + (float)y) * inv_gs;
    P.z = __builtin_amdgcn_exp2f(-(t2 * t2) * LOG2E);
    P.w = __builtin_amdgcn_exp2f(-(t3 * t3) * LOG2E);
    return P;
}

__device__ __forceinline__ float conf_c(const float* __restrict__ out,
                                        int b, int p) {
    int a = p / (GSZ * GSZ), r = p % (GSZ * GSZ);
    int y = r / GSZ, x = r % GSZ;
    const float* base = out + ((((size_t)b * NC + a * 5) * GSZ + y) * GSZ + x);
    float c = f_sigmoid(base[4 * GSZ * GSZ]);
    return fminf(fmaxf(c, 1e-7f), 1.0f - 1e-7f);
}

// K1: decode + fused round-1 per-gt argmax chunk partials + thr bits +
// DIRECT accumulation of all non-tp loss terms. For non-tp preds (393152 of
// 393216) the reference loss needs only (conf, thr): icnt += !thr,
// sbce += !thr * -log(1-c), sarea += !thr * c^2. Those are summed here into
// 3 fp64 partials/block; k_final applies exact per-tp-pred corrections.
// NOTHING per-pred is written to HBM except 1 thr bit / 64 preds.
__global__ __launch_bounds__(256) void k_decode(const float* __restrict__ out,
                                                const float* __restrict__ gts,
                                                unsigned long long* __restrict__ thrbits,
                                                float* __restrict__ pval,
                                                int* __restrict__ ppd,
                                                double* __restrict__ partial) {
    const int tid = threadIdx.x;
    const int b = blockIdx.x / NCHD;          // image
    const int ch = blockIdx.x % NCHD;         // chunk within image
    __shared__ float4 Pl[256];                // decoded preds of this chunk
    __shared__ float4 gbA[MGT];
    __shared__ int glist[MGT];
    __shared__ int ng_s;
    __shared__ double dsum[4][3];

    if (tid < MGT) {
        gbA[tid] = make_float4(gts[tid * 5 + 1], gts[tid * 5 + 2],
                               gts[tid * 5 + 3], gts[tid * 5 + 4]);
        bool v = (gts[tid * 5] == (float)b);
        unsigned long long m = __ballot(v);
        if (v) glist[(int)__popcll(m & ((1ull << tid) - 1ull))] = tid;  // ascending j
        if (tid == 0) ng_s = (int)__popcll(m);
    }

    const int p_loc = ch * 256 + tid;         // pred index within image
    float4 P = decode_P(out, b, p_loc);
    float c = conf_c(out, b, p_loc);
    Pl[tid] = P;
    __syncthreads();

    // per-pred fallback argmax (ascending j, strict > = first max) -> thr.
    const int ng = ng_s;
    bool thr;
    {
        float bg = NEGV, bi = 0.0f;
        for (int m = 0; m < ng; m++) {
            float iu, go; gou_iou(P, gbA[glist[m]], iu, go);
            if (go > bg) { bg = go; bi = iu; }
        }
        thr = (ng > 0) && (bi > 0.5f);        // ng==0 -> pd_ious=0 -> thr=0
        unsigned long long tm = __ballot(thr);
        const int idx = blockIdx.x * 256 + tid;
        if ((tid & 63) == 0) thrbits[idx >> 6] = tm;
    }

    // non-tp loss partials (as if tp=0 for every pred; k_final corrects the
    // <=64 actually-matched preds): ig = !thr here.
    {
        double a0 = 0.0, a1 = 0.0, a2 = 0.0;
        if (!thr) { a0 = 1.0; a1 = (double)(-f_log(1.0f - c)); a2 = (double)c * (double)c; }
        for (int off = 32; off > 0; off >>= 1) {
            a0 += __shfl_down(a0, off, 64);
            a1 += __shfl_down(a1, off, 64);
            a2 += __shfl_down(a2, off, 64);
        }
        if ((tid & 63) == 0) { dsum[tid >> 6][0] = a0; dsum[tid >> 6][1] = a1; dsum[tid >> 6][2] = a2; }
    }
    __syncthreads();
    if (tid < 3)
        partial[blockIdx.x * 3 + tid] =
            dsum[0][tid] + dsum[1][tid] + dsum[2][tid] + dsum[3][tid];

    // per-gt argmax over this 256-pred chunk; wave w handles gts w, w+4, ...
    // Lane l owns preds 4l..4l+3 (ascending) -> strict > keeps first max;
    // cross-lane tiebreak idx-asc -> exact first-occurrence semantics.
    const int wave = tid >> 6, lane = tid & 63;
    for (int m = wave; m < ng; m += 4) {
        float4 g = gbA[glist[m]];
        float bv = NEGV; int bp = 0;
        #pragma unroll
        for (int k = 0; k < 4; k++) {
            int p = lane * 4 + k;
            float iu, go; gou_iou(Pl[p], g, iu, go);
            if (go > bv) { bv = go; bp = p; }
        }
        for (int off = 32; off > 0; off >>= 1) {
            float v2 = __shfl_down(bv, off, 64);
            int   p2 = __shfl_down(bp, off, 64);
            if (v2 > bv || (v2 == bv && p2 < bp)) { bv = v2; bp = p2; }
        }
        if (lane == 0) {
            int j = glist[m];
            pval[j * NCHD + ch] = bv;
            ppd[j * NCHD + ch]  = ch * 256 + bp;   // pred index within image
        }
    }
}

// K2: greedy matching, one workgroup per image. Per-gt state in WAVE-0
// REGISTERS; rounds are ballot+shuffle; block-wide rescans (recomputing P
// from the raw tensor — bit-identical decode_P) only for stolen caches.
// Output: compact match list mpred[b*64+j] = matched pred or -1.
// Replicates the reference while_loop exactly (first-occurrence argmax
// ties, winner scatter-max, first-j Amat selection).
#define MTH 1024
__global__ __launch_bounds__(MTH) void k_match(const float* __restrict__ gts,
                                               const float* __restrict__ pval,
                                               const int* __restrict__ ppd,
                                               const float* __restrict__ out,
                                               int* __restrict__ mpred) {
    const int b = blockIdx.x;
    const int tid = threadIdx.x;
    __shared__ unsigned mbits[NWRD];            // matched-pred bitmask
    __shared__ float4 gb[MGT];
    __shared__ float sh_v[MGT];
    __shared__ int   sh_p[MGT];
    __shared__ float sh_rv[16];
    __shared__ int   sh_rp[16];
    __shared__ unsigned long long sh_need;
    __shared__ int sh_cont;

    for (int i = tid; i < NWRD; i += MTH) mbits[i] = 0u;
    if (tid < MGT)
        gb[tid] = make_float4(gts[tid * 5 + 1], gts[tid * 5 + 2],
                              gts[tid * 5 + 3], gts[tid * 5 + 4]);

    // parallel merge of decode's 192 chunk partials -> per-gt seed.
    // 16 threads per gt, 12 chunks each (ascending chunk = ascending pred:
    // strict > + idx-asc tiebreak == exact first-occurrence argmax).
    {
        int jt = tid >> 4, sub = tid & 15;
        float mv = NEGV; int mp = 0x7FFFFFFF;
        #pragma unroll
        for (int k = 0; k < NCHD / 16; k++) {
            int ch = sub * (NCHD / 16) + k;
            float v2 = pval[jt * NCHD + ch];
            int   p2 = ppd [jt * NCHD + ch];
            if (v2 > mv || (v2 == mv && p2 < mp)) { mv = v2; mp = p2; }
        }
        for (int off = 1; off < 16; off <<= 1) {          // xor-butterfly in 16-group
            float v2 = __shfl_xor(mv, off, 64);
            int   p2 = __shfl_xor(mp, off, 64);
            if (v2 > mv || (v2 == mv && p2 < mp)) { mv = v2; mp = p2; }
        }
        if (sub == 0) { sh_v[jt] = mv; sh_p[jt] = mp; }
    }
    __syncthreads();

    // wave-0 per-gt register state (invalid gts carry poisoned seeds from
    // unwritten pval/ppd rows -> mask them so no garbage LDS index forms)
    bool r_valid = false, r_sel = false;
    float r_cval = NEGV; int r_cpd = 0, r_mp = -1;
    if (tid < 64) {
        r_valid = (gts[tid * 5] == (float)b);
        r_cval = r_valid ? sh_v[tid] : NEGV;
        r_cpd  = r_valid ? sh_p[tid] : 0;
    }

    for (int round = 0; round < MGT + 2; ++round) {
        if (tid < 64) {
            bool active = r_valid && !r_sel;
            unsigned long long am = __ballot(active);
            bool stolen = active && ((mbits[r_cpd >> 5] >> (r_cpd & 31)) & 1u);
            unsigned long long nm = __ballot(stolen);
            if (tid == 0) { sh_cont = (am != 0ull) ? 1 : 0; sh_need = nm; }
        }
        __syncthreads();
        if (!sh_cont) break;
        unsigned long long need = sh_need;

        // rescans: only gts whose cached best pred got stolen (mask only
        // grows, so an un-stolen cached argmax is still exact).
        while (need) {
            int j = __ffsll((long long)need) - 1; need &= need - 1ull;
            float4 g = gb[j];
            float bv = NEGV; int bp = 0x7FFFFFFF;
            for (int p = tid; p < NPRED; p += MTH) {
                if ((mbits[p >> 5] >> (p & 31)) & 1u) continue;
                float iu, go; gou_iou(decode_P(out, b, p), g, iu, go);
                if (go > bv) { bv = go; bp = p; }        // strict > : first max
            }
            for (int off = 32; off > 0; off >>= 1) {
                float v2 = __shfl_down(bv, off, 64);
                int   p2 = __shfl_down(bp, off, 64);
                if (v2 > bv || (v2 == bv && p2 < bp)) { bv = v2; bp = p2; }
            }
            if ((tid & 63) == 0) { sh_rv[tid >> 6] = bv; sh_rp[tid >> 6] = bp; }
            __syncthreads();
            if (tid < 64) {
                float v = (tid < 16) ? sh_rv[tid] : NEGV;
                int   p = (tid < 16) ? sh_rp[tid] : 0x7FFFFFFF;
                for (int off = 1; off < 16; off <<= 1) {
                    float v2 = __shfl_xor(v, off, 64);
                    int   p2 = __shfl_xor(p, off, 64);
                    if (v2 > v || (v2 == v && p2 < p)) { v = v2; p = p2; }
                }
                v = __shfl(v, 0, 64); p = __shfl(p, 0, 64);
                if (tid == j) { r_cval = v; r_cpd = p; }
            }
            __syncthreads();
        }

        // conflict resolution, all in wave-0 registers + shuffles.
        if (tid < 64) {
            bool active = r_valid && !r_sel;
            float valj = active ? r_cval : NEGV;     // reference: inactive -> NEG
            int   pdj  = active ? r_cpd  : 0;        // reference: argmax of all-NEG = 0
            // winner[p] = scatter-max of valj over gts with pdj==p
            float w = NEGV;
            for (int j2 = 0; j2 < 64; j2++) {
                float v2 = __shfl(valj, j2, 64);
                int   p2 = __shfl(pdj,  j2, 64);
                if (p2 == pdj) w = fmaxf(w, v2);
            }
            // Amat first-j: first j2 with pdj2==p && valj2>=w
            unsigned long long fm = 0ull;
            for (int j2 = 0; j2 < 64; j2++) {
                float v2 = __shfl(valj, j2, 64);
                int   p2 = __shfl(pdj,  j2, 64);
                if (p2 == pdj && v2 >= w) fm |= (1ull << j2);
            }
            bool win = active && (w > NEGV * 0.5f) && fm &&
                       ((__ffsll((long long)fm) - 1) == tid);
            if (win) {
                r_sel = true;
                r_mp = pdj;
                atomicOr(&mbits[pdj >> 5], 1u << (pdj & 31));
            }
        }
        __syncthreads();   // mbits visible to all before next round / rescan
    }
    if (tid < 64) mpred[b * MGT + tid] = (r_valid && r_sel) ? r_mp : -1;
}

// K3: single-block finalize. Sums decode's 1536x3 non-tp partials, gathers
// the <=64 matched (pred,gt) pairs (recompute P/c bit-identically), applies
// the exact tp corrections, and writes the 6 fp32 outputs.
//   icnt  = A  + sum_tp (thr ? 1 : 0)
//   sbce  = Bc + sum_tp [ -log(c) - (thr ? 0 : -log(1-c)) ]
//   sarea = C2 + sum_tp (thr ? c^2 : 0)
//   sinter= sum_tp c ;  cnt/gt_area = #tp ;  xy/wh/gou/iou over tp pairs.
__global__ __launch_bounds__(512) void k_final(const float* __restrict__ gts,
                                               const float* __restrict__ out,
                                               const double* __restrict__ partial,
                                               const unsigned long long* __restrict__ thrbits,
                                               const int* __restrict__ mpred,
                                               float* __restrict__ o) {
    __shared__ double wsum[8][9];
    const int tid = threadIdx.x;
    // s: 0 cnt, 1 sxy, 2 swh, 3 sgou, 4 siou, 5 icnt, 6 sbce, 7 sinter, 8 sarea
    double s[9] = {0, 0, 0, 0, 0, 0, 0, 0, 0};

    for (int i = tid; i < DBLK; i += 512) {
        s[5] += partial[i * 3 + 0];
        s[6] += partial[i * 3 + 1];
        s[8] += partial[i * 3 + 2];
    }

    if (tid < NB * MGT) {
        int b = tid >> 6, j = tid & 63;
        int m = mpred[tid];
        if (m >= 0) {
            float4 g = make_float4(gts[j * 5 + 1], gts[j * 5 + 2],
                                   gts[j * 5 + 3], gts[j * 5 + 4]);
            float4 P = decode_P(out, b, m);
            float c = conf_c(out, b, m);
            float pi, pg; gou_iou(P, g, pi, pg);
            int gidx = b * NPRED + m;
            bool f = (thrbits[gidx >> 6] >> (gidx & 63)) & 1;  // decode's thr
            s[0] += 1.0;
            float dx = P.x - g.x, dy = P.y - g.y;
            s[1] += (double)(dx * dx) + (double)(dy * dy);
            float lw = f_log(P.z) - f_log(g.z);
            float lh = f_log(P.w) - f_log(g.w);
            s[2] += (double)(lw * lw) + (double)(lh * lh);
            s[3] += (double)pg;
            s[4] += (double)pi;
            s[5] += f ? 1.0 : 0.0;                    // ig=1 for tp; A counted iff !f
            s[6] += (double)(-f_log(c)) - (f ? 0.0 : (double)(-f_log(1.0f - c)));
            s[7] += (double)c;
            s[8] += f ? (double)c * (double)c : 0.0;  // c^2 counted in C2 iff !f
        }
    }

    for (int k = 0; k < 9; k++) {
        double v = s[k];
        for (int off = 32; off > 0; off >>= 1) v += __shfl_down(v, off, 64);
        s[k] = v;
    }
    if ((tid & 63) == 0)
        for (int k = 0; k < 9; k++) wsum[tid >> 6][k] = s[k];
    __syncthreads();
    if (tid == 0) {
        double acc[9];
        for (int k = 0; k < 9; k++) {
            double v = 0.0;
            for (int w = 0; w < 8; w++) v += wsum[w][k];
            acc[k] = v;
        }
        double cnt_raw = acc[0];
        double cnt = cnt_raw > 1.0 ? cnt_raw : 1.0;
        double lxy  = acc[1] / cnt;
        double lwh  = acc[2] / cnt;
        double lgou = 1.0 - acc[3] / cnt;
        double liou = 1.0 - acc[4] / cnt;
        double icnt = acc[5] > 1.0 ? acc[5] : 1.0;
        double lbce = acc[6] / icnt;
        // gt_area = (tpf*ig).sum() == raw tp count (ig superset of tp), UNclamped
        double ldice = 1.0 - (2.0 * acc[7] + 1.0) / (acc[8] + cnt_raw + 1.0);
        double lconf = ldice + lbce;
        double tot = lconf + 2.0 * lgou + lwh + lxy;
        o[0] = (float)lxy;
        o[1] = (float)lwh;
        o[2] = (float)lconf;
        o[3] = (float)liou;
        o[4] = (float)lgou;
        o[5] = (float)tot;
    }
}

extern "C" void kernel_launch(void* const* d_in, const int* in_sizes, int n_in,
                              void* d_out, int out_size, void* d_ws, size_t ws_size,
                              hipStream_t stream) {
    const float* out_t = (const float*)d_in[0];  // [8,15,128,128]
    const float* gts   = (const float*)d_in[1];  // [64,5]
    char* ws = (char*)d_ws;
    size_t off = 0;
    double*   partial = (double*)(ws + off);    off += (size_t)DBLK * 3 * 8;    // 36864
    float*    pval    = (float*)(ws + off);     off += (size_t)MGT * NCHD * 4;  // 49152
    int*      ppd     = (int*)(ws + off);       off += (size_t)MGT * NCHD * 4;  // 49152
    unsigned long long* thrbits = (unsigned long long*)(ws + off);
    off += (size_t)(NTOT / 64) * 8;                                             // 49152
    int*      mpred   = (int*)(ws + off);       off += (size_t)NB * MGT * 4;    // 2048
    float* o = (float*)d_out;

    k_decode<<<DBLK, 256, 0, stream>>>(out_t, gts, thrbits, pval, ppd, partial);
    k_match <<<NB, MTH, 0, stream>>>(gts, pval, ppd, out_t, mpred);
    k_final <<<1, 512, 0, stream>>>(gts, out_t, partial, thrbits, mpred, o);
}